// Round 1
// baseline (683.295 us; speedup 1.0000x reference)
//
#include <hip/hip_runtime.h>

// ---------------- CSR build ----------------

__global__ __launch_bounds__(256) void k_deg(const int* __restrict__ dst,
                                             int* __restrict__ deg, int E) {
    int i = blockIdx.x * blockDim.x + threadIdx.x;
    if (i < E) atomicAdd(&deg[dst[i]], 1);
}

__global__ __launch_bounds__(256) void k_scan_partials(const int* __restrict__ deg,
                                                       int* __restrict__ bsums, int n) {
    __shared__ int red[256];
    int base = blockIdx.x * 1024 + threadIdx.x * 4;
    int s = 0;
#pragma unroll
    for (int j = 0; j < 4; j++) { int idx = base + j; if (idx < n) s += deg[idx]; }
    red[threadIdx.x] = s;
    __syncthreads();
    for (int off = 128; off > 0; off >>= 1) {
        if (threadIdx.x < off) red[threadIdx.x] += red[threadIdx.x + off];
        __syncthreads();
    }
    if (threadIdx.x == 0) bsums[blockIdx.x] = red[0];
}

__global__ __launch_bounds__(128) void k_scan_bsums(const int* __restrict__ bsums,
                                                    int* __restrict__ boffs, int nblk,
                                                    int* __restrict__ offsets, int n, int E) {
    __shared__ int sd[128];
    int v = (threadIdx.x < nblk) ? bsums[threadIdx.x] : 0;
    sd[threadIdx.x] = v;
    __syncthreads();
    int acc = v;
    for (int off = 1; off < 128; off <<= 1) {
        int t = (threadIdx.x >= off) ? sd[threadIdx.x - off] : 0;
        __syncthreads();
        acc += t;
        sd[threadIdx.x] = acc;
        __syncthreads();
    }
    if (threadIdx.x < nblk) boffs[threadIdx.x] = acc - v;  // exclusive
    if (threadIdx.x == 0) offsets[n] = E;
}

__global__ __launch_bounds__(256) void k_scan_final(const int* __restrict__ deg,
                                                    const int* __restrict__ boffs,
                                                    int* __restrict__ offsets,
                                                    int* __restrict__ cursor,
                                                    float* __restrict__ norm, int n) {
    __shared__ int sd[256];
    int base = blockIdx.x * 1024 + threadIdx.x * 4;
    int v[4];
    int s = 0;
#pragma unroll
    for (int j = 0; j < 4; j++) { int idx = base + j; v[j] = (idx < n) ? deg[idx] : 0; s += v[j]; }
    sd[threadIdx.x] = s;
    __syncthreads();
    int acc = s;
    for (int off = 1; off < 256; off <<= 1) {
        int t = (threadIdx.x >= off) ? sd[threadIdx.x - off] : 0;
        __syncthreads();
        acc += t;
        sd[threadIdx.x] = acc;
        __syncthreads();
    }
    int run = boffs[blockIdx.x] + (acc - s);
#pragma unroll
    for (int j = 0; j < 4; j++) {
        int idx = base + j;
        if (idx < n) {
            offsets[idx] = run;
            cursor[idx]  = run;
            norm[idx]    = 1.0f / ((float)v[j] + 1.0f);
            run += v[j];
        }
    }
}

__global__ __launch_bounds__(256) void k_fill(const int* __restrict__ src,
                                              const int* __restrict__ dst,
                                              int* __restrict__ cursor,
                                              int* __restrict__ cols, int E) {
    int i = blockIdx.x * blockDim.x + threadIdx.x;
    if (i < E) {
        int p = atomicAdd(&cursor[dst[i]], 1);
        cols[p] = src[i];
    }
}

// ---------------- aggregation: t[v] = (h[v] + sum_in h[c]) * norm[v] ----------------
// 32 lanes per node, float4 per lane (128 floats/row). 8 nodes per 256-thread block.

__global__ __launch_bounds__(256) void k_aggregate(const float* __restrict__ h,
                                                   const int* __restrict__ offs,
                                                   const int* __restrict__ cols,
                                                   const float* __restrict__ norm,
                                                   float* __restrict__ t, int n) {
    int node = blockIdx.x * 8 + (threadIdx.x >> 5);
    if (node >= n) return;
    int lane = threadIdx.x & 31;

    const float4* selfrow = (const float4*)(h + (size_t)node * 128);
    float4 acc = selfrow[lane];

    int p = offs[node], e = offs[node + 1];
    for (; p + 2 <= e; p += 2) {
        int c0 = cols[p], c1 = cols[p + 1];
        float4 a = ((const float4*)(h + (size_t)c0 * 128))[lane];
        float4 b = ((const float4*)(h + (size_t)c1 * 128))[lane];
        acc.x += a.x + b.x; acc.y += a.y + b.y; acc.z += a.z + b.z; acc.w += a.w + b.w;
    }
    if (p < e) {
        int c0 = cols[p];
        float4 a = ((const float4*)(h + (size_t)c0 * 128))[lane];
        acc.x += a.x; acc.y += a.y; acc.z += a.z; acc.w += a.w;
    }
    float nm = norm[node];
    acc.x *= nm; acc.y *= nm; acc.z *= nm; acc.w *= nm;
    ((float4*)(t + (size_t)node * 128))[lane] = acc;
}

// ---------------- GEMM: out[m][j] = act(dot(A[m][:128], W[j][:128]) + b[j]) ----------------
// Block tile: 128 nodes x KOUT outputs. 256 threads, per-thread 8xTN register tile.
// LDS holds k-chunk (32) of A transposed [k][m] and W transposed [k][j] (XOR-swizzled).

template <int KOUT, bool RELU>
__global__ __launch_bounds__(256) void k_gemm(const float* __restrict__ A,
                                              const float* __restrict__ W,
                                              const float* __restrict__ bias,
                                              float* __restrict__ out, int n) {
    constexpr int TN = (KOUT == 128) ? 8 : 4;
    __shared__ __align__(16) float tA[32][128];
    __shared__ __align__(16) float WT[32][KOUT];

    int tid  = threadIdx.x;
    int trow = tid >> 4;        // 0..15  -> m sub-tile
    int tcol = tid & 15;        // 0..15  -> j sub-tile
    int m0   = blockIdx.x * 128;
    int mt   = trow * 8;
    int j0   = tcol * TN;
    int sw   = ((j0 >> 5) & 3) << 2;  // XOR swizzle (breaks 4-way bank conflict on W reads)

    float acc[8][TN];
#pragma unroll
    for (int i = 0; i < 8; i++)
#pragma unroll
        for (int j = 0; j < TN; j++) acc[i][j] = 0.f;

    for (int k0 = 0; k0 < 128; k0 += 32) {
        __syncthreads();  // protect LDS from previous iteration's readers
        // stage A chunk, transposed: tA[k][m]
#pragma unroll
        for (int j = 0; j < 4; j++) {
            int idx = tid * 4 + j;
            int q = idx & 7, m = idx >> 3;
            int gm = m0 + m;
            float4 v = make_float4(0.f, 0.f, 0.f, 0.f);
            if (gm < n) v = *(const float4*)(A + (size_t)gm * 128 + k0 + q * 4);
            tA[q * 4 + 0][m] = v.x;
            tA[q * 4 + 1][m] = v.y;
            tA[q * 4 + 2][m] = v.z;
            tA[q * 4 + 3][m] = v.w;
        }
        // stage W chunk, transposed + swizzled: WT[k][f(j)]
#pragma unroll
        for (int j = 0; j < KOUT / 32; j++) {
            int idx = tid * (KOUT / 32) + j;
            int q = idx & 7, jj = idx >> 3;
            float4 v = *(const float4*)(W + (size_t)jj * 128 + k0 + q * 4);
            int js = jj ^ (((jj >> 5) & 3) << 2);
            WT[q * 4 + 0][js] = v.x;
            WT[q * 4 + 1][js] = v.y;
            WT[q * 4 + 2][js] = v.z;
            WT[q * 4 + 3][js] = v.w;
        }
        __syncthreads();

#pragma unroll
        for (int k = 0; k < 32; k++) {
            float a[8], b[TN];
            *(float4*)&a[0] = *(const float4*)&tA[k][mt];
            *(float4*)&a[4] = *(const float4*)&tA[k][mt + 4];
            *(float4*)&b[0] = *(const float4*)&WT[k][j0 ^ sw];
            if constexpr (TN == 8)
                *(float4*)&b[4] = *(const float4*)&WT[k][(j0 + 4) ^ sw];
#pragma unroll
            for (int i = 0; i < 8; i++)
#pragma unroll
                for (int j = 0; j < TN; j++) acc[i][j] = fmaf(a[i], b[j], acc[i][j]);
        }
    }

    float bj[TN];
#pragma unroll
    for (int j = 0; j < TN; j++) bj[j] = bias[j0 + j];

#pragma unroll
    for (int i = 0; i < 8; i++) {
        int gm = m0 + mt + i;
        if (gm < n) {
            float o[TN];
#pragma unroll
            for (int j = 0; j < TN; j++) {
                float v = acc[i][j] + bj[j];
                if (RELU) v = fmaxf(v, 0.f);
                o[j] = v;
            }
            float* op = out + (size_t)gm * KOUT + j0;
            *(float4*)&op[0] = *(const float4*)&o[0];
            if constexpr (TN == 8) *(float4*)&op[4] = *(const float4*)&o[4];
        }
    }
}

// ---------------- launch ----------------

extern "C" void kernel_launch(void* const* d_in, const int* in_sizes, int n_in,
                              void* d_out, int out_size, void* d_ws, size_t ws_size,
                              hipStream_t stream) {
    const float* x  = (const float*)d_in[0];
    const int*  src = (const int*)d_in[1];
    const int*  dst = (const int*)d_in[2];
    const float* W1 = (const float*)d_in[3];
    const float* b1 = (const float*)d_in[4];
    const float* W2 = (const float*)d_in[5];
    const float* b2 = (const float*)d_in[6];
    const float* W3 = (const float*)d_in[7];
    const float* b3 = (const float*)d_in[8];
    float* out = (float*)d_out;

    int n = in_sizes[0] / 128;
    int E = in_sizes[1];

    char* ws = (char*)d_ws;
    size_t off = 0;
    auto alloc = [&](size_t bytes) -> char* {
        char* p = ws + off;
        off += (bytes + 255) & ~(size_t)255;
        return p;
    };
    int*   deg     = (int*)alloc((size_t)n * 4);
    int*   offsets = (int*)alloc(((size_t)n + 1) * 4);
    int*   cursor  = (int*)alloc((size_t)n * 4);
    int*   bsums   = (int*)alloc(512 * 4);
    int*   boffs   = (int*)alloc(512 * 4);
    float* norm    = (float*)alloc((size_t)n * 4);
    int*   cols    = (int*)alloc((size_t)E * 4);
    float* tbuf    = (float*)alloc((size_t)n * 128 * 4);
    float* hbuf    = (float*)alloc((size_t)n * 128 * 4);

    hipMemsetAsync(deg, 0, (size_t)n * 4, stream);

    int nblkE = (E + 255) / 256;
    int nblk1 = (n + 1023) / 1024;
    k_deg<<<nblkE, 256, 0, stream>>>(dst, deg, E);
    k_scan_partials<<<nblk1, 256, 0, stream>>>(deg, bsums, n);
    k_scan_bsums<<<1, 128, 0, stream>>>(bsums, boffs, nblk1, offsets, n, E);
    k_scan_final<<<nblk1, 256, 0, stream>>>(deg, boffs, offsets, cursor, norm, n);
    k_fill<<<nblkE, 256, 0, stream>>>(src, dst, cursor, cols, E);

    int nblkA = (n + 7) / 8;
    int nblkG = (n + 127) / 128;

    // layer 1: x -> t -> h
    k_aggregate<<<nblkA, 256, 0, stream>>>(x, offsets, cols, norm, tbuf, n);
    k_gemm<128, true><<<nblkG, 256, 0, stream>>>(tbuf, W1, b1, hbuf, n);
    // layer 2: h -> t -> h
    k_aggregate<<<nblkA, 256, 0, stream>>>(hbuf, offsets, cols, norm, tbuf, n);
    k_gemm<128, true><<<nblkG, 256, 0, stream>>>(tbuf, W2, b2, hbuf, n);
    // layer 3: h -> t -> out
    k_aggregate<<<nblkA, 256, 0, stream>>>(hbuf, offsets, cols, norm, tbuf, n);
    k_gemm<64, false><<<nblkG, 256, 0, stream>>>(tbuf, W3, b3, out, n);
}